// Round 1
// baseline (136.776 us; speedup 1.0000x reference)
//
#include <hip/hip_runtime.h>
#include <math.h>

// QASA layer: out = (circuit(x @ W_in.T + b_in, q_weights)) @ W_out.T + b_out
// 8 qubits, 256-amplitude state vector, one wave (64 lanes) per batch row.
// State layout: idx = lane*4 + r  (bits [7:2]=lane, [1:0]=register r).
// Wire i acts on bit (7-i) of idx.

__device__ __forceinline__ float shxor(float v, int mask) {
    return __shfl_xor(v, mask, 64);
}

// RX(theta) on bit B: a' = c*a - i*s*partner  (c=cos(th/2), s=sin(th/2))
template <int B>
__device__ __forceinline__ void rx_gate(float re[4], float im[4], float c, float s, int lane) {
    if constexpr (B >= 2) {
        constexpr int mask = 1 << (B - 2);
#pragma unroll
        for (int r = 0; r < 4; ++r) {
            float pre = shxor(re[r], mask);
            float pim = shxor(im[r], mask);
            float nre = c * re[r] + s * pim;
            float nim = c * im[r] - s * pre;
            re[r] = nre; im[r] = nim;
        }
    } else {
        constexpr int P = (B == 1) ? 2 : 1;
        float nre[4], nim[4];
#pragma unroll
        for (int r = 0; r < 4; ++r) {
            nre[r] = c * re[r] + s * im[r ^ P];
            nim[r] = c * im[r] - s * re[r ^ P];
        }
#pragma unroll
        for (int r = 0; r < 4; ++r) { re[r] = nre[r]; im[r] = nim[r]; }
    }
}

// RZ(theta) on bit B: amp *= exp(+i*th/2) if bit==1 else exp(-i*th/2)
template <int B>
__device__ __forceinline__ void rz_gate(float re[4], float im[4], float c, float s, int lane) {
    if constexpr (B >= 2) {
        float ss = ((lane >> (B - 2)) & 1) ? s : -s;
#pragma unroll
        for (int r = 0; r < 4; ++r) {
            float nre = c * re[r] - ss * im[r];
            float nim = c * im[r] + ss * re[r];
            re[r] = nre; im[r] = nim;
        }
    } else {
#pragma unroll
        for (int r = 0; r < 4; ++r) {
            float ss = ((r >> B) & 1) ? s : -s;
            float nre = c * re[r] - ss * im[r];
            float nim = c * im[r] + ss * re[r];
            re[r] = nre; im[r] = nim;
        }
    }
}

// CNOT: control bit BC, target bit BT (here always BC == BT+1)
template <int BC, int BT>
__device__ __forceinline__ void cnot_gate(float re[4], float im[4], int lane) {
    if constexpr (BT >= 2) {
        constexpr int mask = 1 << (BT - 2);
        bool ctrl = (lane >> (BC - 2)) & 1;
#pragma unroll
        for (int r = 0; r < 4; ++r) {
            float pre = shxor(re[r], mask);
            float pim = shxor(im[r], mask);
            re[r] = ctrl ? pre : re[r];
            im[r] = ctrl ? pim : im[r];
        }
    } else if constexpr (BT == 1) {
        // BC==2 -> control = lane bit 0; swap regs (0,2) and (1,3) where ctrl
        bool ctrl = lane & 1;
#pragma unroll
        for (int r = 0; r < 2; ++r) {
            float a = re[r], b = re[r + 2];
            re[r] = ctrl ? b : a; re[r + 2] = ctrl ? a : b;
            float ai = im[r], bi = im[r + 2];
            im[r] = ctrl ? bi : ai; im[r + 2] = ctrl ? ai : bi;
        }
    } else {
        // BT==0, BC==1 -> control = reg bit 1: swap regs 2 and 3 (all lanes)
        float t = re[2]; re[2] = re[3]; re[3] = t;
        t = im[2]; im[2] = im[3]; im[3] = t;
    }
}

#define ROT(I, C1, S1, C2, S2)                        \
    rx_gate<7 - (I)>(re, im, (C1), (S1), lane);       \
    rz_gate<7 - (I)>(re, im, (C2), (S2), lane);

__global__ void __launch_bounds__(256) qasa_kernel(
    const float* __restrict__ x, const float* __restrict__ W_in,
    const float* __restrict__ b_in, const float* __restrict__ qw,
    const float* __restrict__ W_out, const float* __restrict__ b_out,
    float* __restrict__ out)
{
    __shared__ float4 w_lds4[2048];   // 32 KB: W_in, then reused for W_out (A|B split)
    __shared__ float wc[64];
    __shared__ float ws[64];
    __shared__ float b_in_s[8];

    float* w_lds = (float*)w_lds4;
    const int tid = threadIdx.x;
    const int lane = tid & 63;
    const int wave = tid >> 6;
    const size_t row = (size_t)blockIdx.x * 4 + wave;

    // ---- stage W_in [8][1024] into LDS (2048 float4, 256 threads x 8) ----
    {
        const float4* src = (const float4*)W_in;
#pragma unroll
        for (int k = 0; k < 8; ++k) w_lds4[tid + 256 * k] = src[tid + 256 * k];
    }
    if (tid < 64) {
        float sv, cv;
        __sincosf(0.5f * qw[tid], &sv, &cv);
        wc[tid] = cv; ws[tid] = sv;
    }
    if (tid < 8) b_in_s[tid] = b_in[tid];
    __syncthreads();

    // ---- phase 1: angles = x[row] @ W_in.T + b_in ----
    float ang[8];
    {
        float acc[8] = {0.f, 0.f, 0.f, 0.f, 0.f, 0.f, 0.f, 0.f};
        const float4* xrow = (const float4*)(x + row * 1024);
#pragma unroll
        for (int k = 0; k < 4; ++k) {
            float4 xv = xrow[lane + 64 * k];
#pragma unroll
            for (int q = 0; q < 8; ++q) {
                float4 wv = ((const float4*)w_lds)[q * 256 + lane + 64 * k];
                acc[q] += xv.x * wv.x + xv.y * wv.y + xv.z * wv.z + xv.w * wv.w;
            }
        }
#pragma unroll
        for (int q = 0; q < 8; ++q) {
#pragma unroll
            for (int m = 1; m < 64; m <<= 1) acc[q] += shxor(acc[q], m);
            ang[q] = acc[q] + b_in_s[q];
        }
    }
    __syncthreads();  // phase-1 LDS reads done before overwrite

    // ---- stage W_out [1024][8] into LDS as A[col]=q0..3, B[col]=q4..7 ----
    {
        const float4* src = (const float4*)W_out;
        float4* A = w_lds4;
        float4* Bv = w_lds4 + 1024;
#pragma unroll
        for (int k = 0; k < 4; ++k) {
            int col = tid + 256 * k;
            A[col] = src[2 * col];
            Bv[col] = src[2 * col + 1];
        }
    }

    // ---- phase 2: simulate the circuit ----
    float re[4], im[4];
#pragma unroll
    for (int r = 0; r < 4; ++r) { re[r] = 0.f; im[r] = 0.f; }
    re[0] = (lane == 0) ? 1.f : 0.f;

    {   // initial embedding: RX(ang[i]) then RZ(ang[i]) on wire i
        float cv[8], sv[8];
#pragma unroll
        for (int i = 0; i < 8; ++i) __sincosf(0.5f * ang[i], &sv[i], &cv[i]);
        ROT(0, cv[0], sv[0], cv[0], sv[0])
        ROT(1, cv[1], sv[1], cv[1], sv[1])
        ROT(2, cv[2], sv[2], cv[2], sv[2])
        ROT(3, cv[3], sv[3], cv[3], sv[3])
        ROT(4, cv[4], sv[4], cv[4], sv[4])
        ROT(5, cv[5], sv[5], cv[5], sv[5])
        ROT(6, cv[6], sv[6], cv[6], sv[6])
        ROT(7, cv[7], sv[7], cv[7], sv[7])
    }

#pragma unroll 1
    for (int l = 0; l < 4; ++l) {
        const float* lc = wc + l * 16;
        const float* lsn = ws + l * 16;
        // RX(weights[l,0,i]); RZ(weights[l,1,i]) on wire i
        ROT(0, lc[0], lsn[0], lc[8],  lsn[8])
        ROT(1, lc[1], lsn[1], lc[9],  lsn[9])
        ROT(2, lc[2], lsn[2], lc[10], lsn[10])
        ROT(3, lc[3], lsn[3], lc[11], lsn[11])
        ROT(4, lc[4], lsn[4], lc[12], lsn[12])
        ROT(5, lc[5], lsn[5], lc[13], lsn[13])
        ROT(6, lc[6], lsn[6], lc[14], lsn[14])
        ROT(7, lc[7], lsn[7], lc[15], lsn[15])
        // CNOT chain: control i, target i+1  -> bits (7-i, 6-i)
        cnot_gate<7, 6>(re, im, lane);
        cnot_gate<6, 5>(re, im, lane);
        cnot_gate<5, 4>(re, im, lane);
        cnot_gate<4, 3>(re, im, lane);
        cnot_gate<3, 2>(re, im, lane);
        cnot_gate<2, 1>(re, im, lane);
        cnot_gate<1, 0>(re, im, lane);
    }

    // ---- phase 3: expvals <Z_i> ----
    float p0 = re[0] * re[0] + im[0] * im[0];
    float p1 = re[1] * re[1] + im[1] * im[1];
    float p2 = re[2] * re[2] + im[2] * im[2];
    float p3 = re[3] * re[3] + im[3] * im[3];
    float psum = (p0 + p1) + (p2 + p3);
    float s6 = (p0 + p1) - (p2 + p3);   // wire 6: reg bit 1
    float s7 = (p0 + p2) - (p1 + p3);   // wire 7: reg bit 0

    float ev[8];
#pragma unroll
    for (int q = 0; q < 8; ++q) {
        float e;
        if (q < 6) {
            int lb = 5 - q;  // wire q -> idx bit 7-q -> lane bit 5-q
            e = ((lane >> lb) & 1) ? -psum : psum;
        } else if (q == 6) e = s6;
        else e = s7;
#pragma unroll
        for (int m = 1; m < 64; m <<= 1) e += shxor(e, m);
        ev[q] = e;
    }

    // ---- phase 4: out[row] = ev @ W_out.T + b_out ----
    __syncthreads();  // W_out staging complete (writes happened before circuit)
    const float4* A = (const float4*)w_lds4;
    const float4* Bv = ((const float4*)w_lds4) + 1024;
    float* orow = out + row * 1024;
#pragma unroll
    for (int j = 0; j < 16; ++j) {
        int col = lane + 64 * j;
        float4 a = A[col];
        float4 b = Bv[col];
        float o = b_out[col]
            + a.x * ev[0] + a.y * ev[1] + a.z * ev[2] + a.w * ev[3]
            + b.x * ev[4] + b.y * ev[5] + b.z * ev[6] + b.w * ev[7];
        orow[col] = o;
    }
}

extern "C" void kernel_launch(void* const* d_in, const int* in_sizes, int n_in,
                              void* d_out, int out_size, void* d_ws, size_t ws_size,
                              hipStream_t stream) {
    const float* x     = (const float*)d_in[0];
    const float* W_in  = (const float*)d_in[1];
    const float* b_in  = (const float*)d_in[2];
    const float* qw    = (const float*)d_in[3];
    const float* W_out = (const float*)d_in[4];
    const float* b_out = (const float*)d_in[5];
    float* outp = (float*)d_out;

    const int B = in_sizes[0] / 1024;   // 8192
    const int grid = B / 4;             // 4 rows (waves) per 256-thread block
    qasa_kernel<<<grid, 256, 0, stream>>>(x, W_in, b_in, qw, W_out, b_out, outp);
}